// Round 8
// baseline (1350.170 us; speedup 1.0000x reference)
//
#include <hip/hip_runtime.h>
#include <hip/hip_bf16.h>

// NNConv GNN, round 8 — aggregation-before-GEMM restructure:
//   agg[i] = sum_k (sum_{e->i} ek_k h_src) @ K_k + (sum_{e->i} h_src) @ B
// Per 15-node dst tile (one 512-thread block):
//   phase 1: waves stride the tile's contiguous dst-CSR slot range; per slot
//     gather h[src] (coalesced 256B, L2-hot), scalar eks row, accumulate
//     z[17] in registers; flush to LDS Zt[15][1092] via ds atomics on node
//     change. No per-edge LDS reads, no scattered global stores.
//   phase 2: C = [Zt | h_tile] @ GwT via split-bf16 MFMA (K=1088 from LDS +
//     K=64 root extension from hhi/hlo), 8 waves = 4 n-strips x 2 K-halves,
//     partial combine through LDS, fused mean/root/bias/relu epilogue writes
//     h, hhi, hlo directly. msg/agg/Proot/P buffers all eliminated.

#define NN 20000
#define NE 100000
#define WD 64
#define DEPTH 6
#define TM 15            // dst nodes per tile
#define ZSTR 1092        // Zt row stride (words); 1092%32==4 breaks bank aliasing

typedef __attribute__((ext_vector_type(8))) short bf16x8;
typedef __attribute__((ext_vector_type(4))) float f32x4;

__device__ __forceinline__ unsigned short f2bf(float v) {
    union { float f; unsigned u; } x; x.f = v;
    unsigned r = x.u + 0x7fffu + ((x.u >> 16) & 1u);
    return (unsigned short)(r >> 16);
}
__device__ __forceinline__ float bf2f(unsigned short b) {
    union { unsigned u; float f; } x; x.u = ((unsigned)b) << 16;
    return x.f;
}

// ---------------- in-degree counts ----------------
__global__ __launch_bounds__(256) void count_kernel(const int* __restrict__ ei,
                                                    int* __restrict__ inc)
{
    int e = blockIdx.x * 256 + threadIdx.x;
    if (e >= NE) return;
    atomicAdd(&inc[ei[NE + e]], 1);
}

// ---------------- hierarchical scan over inc (20000 ints) ----------
__global__ __launch_bounds__(256) void scanA_kernel(const int* __restrict__ cnt,
                                                    int* __restrict__ partials)
{
    int b = blockIdx.x, t = threadIdx.x, lane = t & 63, w = t >> 6;
    int base = b * 1024 + t * 4;
    int s = 0;
#pragma unroll
    for (int i = 0; i < 4; ++i) {
        int idx = base + i;
        if (idx < NN) s += cnt[idx];
    }
#pragma unroll
    for (int off = 32; off > 0; off >>= 1) s += __shfl_down(s, off, 64);
    __shared__ int wsum[4];
    if (lane == 0) wsum[w] = s;
    __syncthreads();
    if (t == 0) partials[b] = wsum[0] + wsum[1] + wsum[2] + wsum[3];
}

__global__ __launch_bounds__(64) void scanB_kernel(const int* __restrict__ partials,
                                                   int* __restrict__ bases)
{
    int l = threadIdx.x;
    int p = (l < 20) ? partials[l] : 0;
    int v = p;
#pragma unroll
    for (int off = 1; off < 64; off <<= 1) {
        int u = __shfl_up(v, off, 64);
        if (l >= off) v += u;
    }
    if (l < 20) bases[l] = v - p;   // exclusive
}

__global__ __launch_bounds__(256) void scanC_kernel(const int* __restrict__ cnt,
                                                    const int* __restrict__ bases,
                                                    int* __restrict__ rpd,
                                                    float* __restrict__ invd)
{
    int b = blockIdx.x, t = threadIdx.x, lane = t & 63, w = t >> 6;
    int base = b * 1024 + t * 4;
    int v[4], s = 0;
#pragma unroll
    for (int i = 0; i < 4; ++i) {
        int idx = base + i;
        v[i] = (idx < NN) ? cnt[idx] : 0;
        s += v[i];
    }
    int tsum = s, sc = s;
#pragma unroll
    for (int off = 1; off < 64; off <<= 1) {
        int u = __shfl_up(sc, off, 64);
        if (lane >= off) sc += u;
    }
    __shared__ int wtot[4];
    if (lane == 63) wtot[w] = sc;
    __syncthreads();
    int wbase = 0;
    for (int j = 0; j < w; ++j) wbase += wtot[j];
    int run = bases[b] + wbase + sc - tsum;
#pragma unroll
    for (int i = 0; i < 4; ++i) {
        int idx = base + i;
        int e = run; run += v[i];
        if (idx < NN) {
            rpd[idx] = e;
            invd[idx] = 1.0f / fmaxf((float)v[i], 1.0f);
        }
    }
    if (b == 0 && t == 0) rpd[NN] = NE;
}

// ---------------- ek MLP + dst-CSR fill ----------------
__global__ __launch_bounds__(256) void ekfill_kernel(
    const int* __restrict__ ei, const float* __restrict__ ea,
    const float* __restrict__ k1w, const float* __restrict__ k1b,
    const int* __restrict__ rpd, int* __restrict__ fd,
    float* __restrict__ eks, int* __restrict__ srcs)
{
    int e = blockIdx.x * 256 + threadIdx.x;
    if (e >= NE) return;
    int s = ei[e], d = ei[NE + e];
    float a[6];
#pragma unroll
    for (int i = 0; i < 6; ++i) a[i] = ea[e * 6 + i];
    int slot = rpd[d] + atomicAdd(&fd[d], 1);
    srcs[slot] = s;
#pragma unroll
    for (int j = 0; j < 16; ++j) {
        float v = k1b[j];
#pragma unroll
        for (int i = 0; i < 6; ++i) v = fmaf(a[i], k1w[i * 16 + j], v);
        eks[(size_t)slot * 16 + j] = fmaxf(v, 0.f);
    }
}

// ---------------- GwT hi/lo bf16, [64 out rows][1152 k cols] ---------------
// k = k16*64 + e for k16<17 (16 kernel blocks + bias), k=1088+e for root.
__global__ __launch_bounds__(256) void gwt_kernel(
    const float* __restrict__ k2w, const float* __restrict__ k2b,
    const float* __restrict__ rootw,
    unsigned short* __restrict__ Gh, unsigned short* __restrict__ Gl)
{
    int idx = blockIdx.x * 256 + threadIdx.x;   // 64*1152
    if (idx >= 64 * 1152) return;
    int o = idx / 1152, c = idx % 1152;
    float g;
    if (c < 1024)       g = k2w[(c >> 6) * 4096 + (c & 63) * 64 + o];
    else if (c < 1088)  g = k2b[(c & 63) * 64 + o];
    else                g = rootw[(c - 1088) * 64 + o];
    unsigned short hi = f2bf(g);
    Gh[idx] = hi;
    Gl[idx] = f2bf(g - bf2f(hi));
}

// ---------------- h0 = x*fc1_w + fc1_b -> h fp32 + hi/lo bf16 ---------------
__global__ __launch_bounds__(256) void h0_kernel(
    const float* __restrict__ x, const float* __restrict__ w,
    const float* __restrict__ b, float* __restrict__ h,
    unsigned short* __restrict__ hhi, unsigned short* __restrict__ hlo)
{
    int idx = blockIdx.x * 256 + threadIdx.x;
    if (idx >= NN * WD) return;
    int n = idx >> 6, o = idx & 63;
    float v = fmaf(x[n], w[o], b[o]);
    h[idx] = v;
    unsigned short hi = f2bf(v);
    hhi[idx] = hi;
    hlo[idx] = f2bf(v - bf2f(hi));
}

// ---------------- fused: edge-aggregate Z -> MFMA GEMM -> epilogue ----------
__global__ __launch_bounds__(512) void fused2_kernel(
    const float* __restrict__ h, const unsigned short* __restrict__ hhi,
    const unsigned short* __restrict__ hlo,
    const unsigned short* __restrict__ Gh, const unsigned short* __restrict__ Gl,
    const float* __restrict__ eks, const int* __restrict__ srcs,
    const int* __restrict__ rpd, const float* __restrict__ invd,
    const float* __restrict__ convb, float* __restrict__ hout,
    unsigned short* __restrict__ hhio, unsigned short* __restrict__ hloo)
{
    __shared__ __align__(16) float Zt[TM * ZSTR];   // 65,520 B
    __shared__ int rb[TM + 1];
    int n0 = blockIdx.x * TM;
    int tid = threadIdx.x;
    int w = tid >> 6, l = tid & 63;
    int quad = l >> 4, lr = l & 15;
    if (tid < TM + 1) {
        int gi = n0 + tid;
        rb[tid] = rpd[gi > NN ? NN : gi];
    }
    for (int i = tid; i < TM * ZSTR; i += 512) Zt[i] = 0.f;
    __syncthreads();

    // ---- phase 1: per-wave contiguous dst-slot sub-ranges ----
    int nend = n0 + TM; if (nend > NN) nend = NN;
    int tmeff = nend - n0;
    int r0 = rb[0], r1 = rb[tmeff];
    int total = r1 - r0;
    if (total > 0) {
        int per = (total + 7) >> 3;
        int s0 = r0 + w * per;
        int s1 = s0 + per; if (s1 > r1) s1 = r1;
        if (s0 < s1) {
            int ln = 0;
            while (s0 >= rb[ln + 1]) ++ln;
            float z[17];
#pragma unroll
            for (int k = 0; k < 17; ++k) z[k] = 0.f;
            bool dirty = false;
            for (int s = s0; s < s1; ++s) {
                if (s >= rb[ln + 1]) {
                    if (dirty) {
#pragma unroll
                        for (int k = 0; k < 17; ++k)
                            atomicAdd(&Zt[ln * ZSTR + k * 64 + l], z[k]);
#pragma unroll
                        for (int k = 0; k < 17; ++k) z[k] = 0.f;
                        dirty = false;
                    }
                    while (s >= rb[ln + 1]) ++ln;
                }
                int su = __builtin_amdgcn_readfirstlane(s);
                int sn = srcs[su];
                float hv = h[(size_t)sn * 64 + l];
                const float* er = eks + (size_t)su * 16;
                f32x4 e0 = *(const f32x4*)(er);
                f32x4 e1 = *(const f32x4*)(er + 4);
                f32x4 e2 = *(const f32x4*)(er + 8);
                f32x4 e3 = *(const f32x4*)(er + 12);
                z[0]  = fmaf(e0[0], hv, z[0]);   z[1]  = fmaf(e0[1], hv, z[1]);
                z[2]  = fmaf(e0[2], hv, z[2]);   z[3]  = fmaf(e0[3], hv, z[3]);
                z[4]  = fmaf(e1[0], hv, z[4]);   z[5]  = fmaf(e1[1], hv, z[5]);
                z[6]  = fmaf(e1[2], hv, z[6]);   z[7]  = fmaf(e1[3], hv, z[7]);
                z[8]  = fmaf(e2[0], hv, z[8]);   z[9]  = fmaf(e2[1], hv, z[9]);
                z[10] = fmaf(e2[2], hv, z[10]);  z[11] = fmaf(e2[3], hv, z[11]);
                z[12] = fmaf(e3[0], hv, z[12]);  z[13] = fmaf(e3[1], hv, z[13]);
                z[14] = fmaf(e3[2], hv, z[14]);  z[15] = fmaf(e3[3], hv, z[15]);
                z[16] += hv;
                dirty = true;
            }
            if (dirty) {
#pragma unroll
                for (int k = 0; k < 17; ++k)
                    atomicAdd(&Zt[ln * ZSTR + k * 64 + l], z[k]);
            }
        }
    }
    __syncthreads();

    // ---- phase 2: C = [Zt | h_tile] @ GwT, strips x K-halves ----
    int st = w & 3, kh = w >> 2;
    int brow = st * 16 + lr;                       // B row = output col
    int rowA = (lr < tmeff) ? lr : 0;              // clamp; garbage discarded
    f32x4 acc = (f32x4){0.f, 0.f, 0.f, 0.f};
    for (int ks = kh * 17; ks < kh * 17 + 17; ++ks) {
        // A fragment: Zt row fp32 -> split bf16
        const f32x4* pz = (const f32x4*)&Zt[rowA * ZSTR + ks * 32 + quad * 8];
        f32x4 z0 = pz[0], z1 = pz[1];
        bf16x8 ah, al;
#pragma unroll
        for (int j = 0; j < 4; ++j) {
            unsigned short hi0 = f2bf(z0[j]);
            ah[j] = (short)hi0; al[j] = (short)f2bf(z0[j] - bf2f(hi0));
            unsigned short hi1 = f2bf(z1[j]);
            ah[4 + j] = (short)hi1; al[4 + j] = (short)f2bf(z1[j] - bf2f(hi1));
        }
        const bf16x8* pbh = (const bf16x8*)(Gh + (size_t)brow * 1152 + ks * 32 + quad * 8);
        const bf16x8* pbl = (const bf16x8*)(Gl + (size_t)brow * 1152 + ks * 32 + quad * 8);
        bf16x8 bh = pbh[0], bl = pbl[0];
        acc = __builtin_amdgcn_mfma_f32_16x16x32_bf16(ah, bh, acc, 0, 0, 0);
        acc = __builtin_amdgcn_mfma_f32_16x16x32_bf16(ah, bl, acc, 0, 0, 0);
        acc = __builtin_amdgcn_mfma_f32_16x16x32_bf16(al, bh, acc, 0, 0, 0);
    }
    // root extension (kh==1 waves): A = h_tile bf16, B rows k 1088..1151
    f32x4 accR = (f32x4){0.f, 0.f, 0.f, 0.f};
    if (kh == 1) {
        int arow = n0 + lr;
        if (arow > NN - 1) arow = NN - 1;
#pragma unroll
        for (int ks2 = 0; ks2 < 2; ++ks2) {
            const bf16x8* pah = (const bf16x8*)(hhi + (size_t)arow * 64 + ks2 * 32 + quad * 8);
            const bf16x8* pal = (const bf16x8*)(hlo + (size_t)arow * 64 + ks2 * 32 + quad * 8);
            bf16x8 ah = pah[0], al = pal[0];
            const bf16x8* pbh = (const bf16x8*)(Gh + (size_t)brow * 1152 + 1088 + ks2 * 32 + quad * 8);
            const bf16x8* pbl = (const bf16x8*)(Gl + (size_t)brow * 1152 + 1088 + ks2 * 32 + quad * 8);
            bf16x8 bh = pbh[0], bl = pbl[0];
            accR = __builtin_amdgcn_mfma_f32_16x16x32_bf16(ah, bh, accR, 0, 0, 0);
            accR = __builtin_amdgcn_mfma_f32_16x16x32_bf16(ah, bl, accR, 0, 0, 0);
            accR = __builtin_amdgcn_mfma_f32_16x16x32_bf16(al, bh, accR, 0, 0, 0);
        }
    }
    __syncthreads();
    // kh==0 waves park partials in (now-dead) Zt
    if (kh == 0) {
#pragma unroll
        for (int r = 0; r < 4; ++r)
            Zt[st * 256 + (quad * 4 + r) * 16 + lr] = acc[r];
    }
    __syncthreads();
    if (kh == 1) {
        int col = st * 16 + lr;
        float cb = convb[col];
#pragma unroll
        for (int r = 0; r < 4; ++r) {
            int row = quad * 4 + r;
            int gn = n0 + row;
            if (row < tmeff) {
                float aggv = acc[r] + Zt[st * 256 + row * 16 + lr];
                float v = fmaf(aggv, invd[gn], accR[r] + cb);
                v = fmaxf(v, 0.f);
                size_t idx = (size_t)gn * 64 + col;
                hout[idx] = v;
                unsigned short hi = f2bf(v);
                hhio[idx] = hi;
                hloo[idx] = f2bf(v - bf2f(hi));
            }
        }
    }
}

// ---------------- out = h @ fc2_w + fc2_b ----------------
__global__ __launch_bounds__(256) void out_kernel(
    const float* __restrict__ h, const float* __restrict__ fc2_w,
    const float* __restrict__ fc2_b, float* __restrict__ out)
{
    int wave = blockIdx.x * 4 + (threadIdx.x >> 6);
    int lane = threadIdx.x & 63;
    float v = h[(size_t)wave * 64 + lane] * fc2_w[lane];
#pragma unroll
    for (int off = 32; off > 0; off >>= 1) v += __shfl_down(v, off);
    if (lane == 0) out[wave] = v + fc2_b[0];
}

extern "C" void kernel_launch(void* const* d_in, const int* in_sizes, int n_in,
                              void* d_out, int out_size, void* d_ws, size_t ws_size,
                              hipStream_t stream)
{
    const float* x         = (const float*)d_in[0];
    const int*   ei        = (const int*)  d_in[1];
    const float* edge_attr = (const float*)d_in[2];
    const float* fc1_w     = (const float*)d_in[3];
    const float* fc1_b     = (const float*)d_in[4];
    const float* k1_w      = (const float*)d_in[5];
    const float* k1_b      = (const float*)d_in[6];
    const float* k2_w      = (const float*)d_in[7];
    const float* k2_b      = (const float*)d_in[8];
    const float* root_w    = (const float*)d_in[9];
    const float* conv_b    = (const float*)d_in[10];
    const float* fc2_w     = (const float*)d_in[11];
    const float* fc2_b     = (const float*)d_in[12];
    float* out = (float*)d_out;

    // workspace layout, f32 units
    float* ws = (float*)d_ws;
    size_t off = 0;
    int* cnt   = (int*)(ws + off); off += 2 * NN;       // inc | fd
    int* inc   = cnt;
    int* fd    = cnt + NN;
    int* rpd   = (int*)(ws + off); off += 20004;
    int* partials = (int*)(ws + off); off += 64;
    int* bases    = (int*)(ws + off); off += 64;
    int* srcs  = (int*)(ws + off); off += NE;
    float* invd  = ws + off; off += NN;
    float* eks   = ws + off; off += (size_t)NE * 16;
    unsigned short* Gh  = (unsigned short*)(ws + off); off += 36864;  // 64*1152 shorts
    unsigned short* Gl  = (unsigned short*)(ws + off); off += 36864;
    unsigned short* hhiA = (unsigned short*)(ws + off); off += (size_t)NN * 32;
    unsigned short* hloA = (unsigned short*)(ws + off); off += (size_t)NN * 32;
    unsigned short* hhiB = (unsigned short*)(ws + off); off += (size_t)NN * 32;
    unsigned short* hloB = (unsigned short*)(ws + off); off += (size_t)NN * 32;
    float* hA    = ws + off; off += (size_t)NN * WD;
    float* hB    = ws + off; off += (size_t)NN * WD;

    hipMemsetAsync(cnt, 0, 2 * NN * sizeof(int), stream);
    count_kernel<<<(NE + 255) / 256, 256, 0, stream>>>(ei, inc);
    scanA_kernel<<<20, 256, 0, stream>>>(inc, partials);
    scanB_kernel<<<1, 64, 0, stream>>>(partials, bases);
    scanC_kernel<<<20, 256, 0, stream>>>(inc, bases, rpd, invd);
    ekfill_kernel<<<(NE + 255) / 256, 256, 0, stream>>>(ei, edge_attr, k1_w, k1_b,
                                                        rpd, fd, eks, srcs);
    gwt_kernel<<<(64 * 1152 + 255) / 256, 256, 0, stream>>>(k2_w, k2_b, root_w, Gh, Gl);
    h0_kernel<<<(NN * WD + 255) / 256, 256, 0, stream>>>(x, fc1_w, fc1_b, hA, hhiA, hloA);

    int ntiles = (NN + TM - 1) / TM;   // 1334
    float* hin = hA;  unsigned short* hhi_i = hhiA; unsigned short* hlo_i = hloA;
    float* hto = hB;  unsigned short* hhi_o = hhiB; unsigned short* hlo_o = hloB;
    for (int layer = 0; layer < DEPTH; ++layer) {
        fused2_kernel<<<ntiles, 512, 0, stream>>>(hin, hhi_i, hlo_i, Gh, Gl,
                                                  eks, srcs, rpd, invd, conv_b,
                                                  hto, hhi_o, hlo_o);
        float* tf = hin; hin = hto; hto = tf;
        unsigned short* t1 = hhi_i; hhi_i = hhi_o; hhi_o = t1;
        unsigned short* t2 = hlo_i; hlo_i = hlo_o; hlo_o = t2;
    }

    out_kernel<<<NN / 4, 256, 0, stream>>>(hin, fc2_w, fc2_b, out);
}

// Round 9
// 619.762 us; speedup vs baseline: 2.1785x; 2.1785x over previous
//
#include <hip/hip_runtime.h>
#include <hip/hip_bf16.h>

// NNConv GNN, round 9 — R7 structure, edge phase on the vector-memory path:
//  Fused per-layer kernel: 512-thread blocks own a 15-node tile. 8 waves
//  compute P_tile = h_tile @ [K_0..K_15|Bmat] via split-bf16 MFMA into LDS
//  (65,520 B; P never touches HBM) + Proot strip to global. Edge phase:
//  per-wave CONTIGUOUS slot sub-range, two-level loop (outer = src node ->
//  P row into registers; inner = slots), eks/ss2sd loaded per-lane from a
//  wave-uniform address (vector path, vmcnt-pipelined, 2x unrolled) — R7's
//  readfirstlane+s_load version serialized on scalar-cache misses.
//  msg scattered to dst-CSR order so agg streams coalesced.
//  CSR built per call: count -> hierarchical 3-kernel scan -> fill.

#define NN 20000
#define NE 100000
#define WD 64
#define DEPTH 6
#define TM 15            // nodes per tile (row 15 of the MFMA tile wasted)
#define LSTR 1092        // LDS row stride (words): 1092%32==4 -> 2-way only

typedef __attribute__((ext_vector_type(8))) short bf16x8;
typedef __attribute__((ext_vector_type(4))) float f32x4;

__device__ __forceinline__ unsigned short f2bf(float v) {
    union { float f; unsigned u; } x; x.f = v;
    unsigned r = x.u + 0x7fffu + ((x.u >> 16) & 1u);
    return (unsigned short)(r >> 16);
}
__device__ __forceinline__ float bf2f(unsigned short b) {
    union { unsigned u; float f; } x; x.u = ((unsigned)b) << 16;
    return x.f;
}

// ---------------- per-node in/out degree counts ----------------
__global__ __launch_bounds__(256) void count_kernel(const int* __restrict__ ei,
                                                    int* __restrict__ outc,
                                                    int* __restrict__ inc)
{
    int e = blockIdx.x * 256 + threadIdx.x;
    if (e >= NE) return;
    atomicAdd(&outc[ei[e]], 1);
    atomicAdd(&inc[ei[NE + e]], 1);
}

// ---------------- hierarchical scan over [outc | inc] (40000 ints) ----------
__global__ __launch_bounds__(256) void scanA_kernel(const int* __restrict__ cnt,
                                                    int* __restrict__ partials)
{
    int b = blockIdx.x, t = threadIdx.x, lane = t & 63, w = t >> 6;
    int base = b * 1024 + t * 4;
    int s = 0;
#pragma unroll
    for (int i = 0; i < 4; ++i) {
        int idx = base + i;
        if (idx < 2 * NN) s += cnt[idx];
    }
#pragma unroll
    for (int off = 32; off > 0; off >>= 1) s += __shfl_down(s, off, 64);
    __shared__ int wsum[4];
    if (lane == 0) wsum[w] = s;
    __syncthreads();
    if (t == 0) partials[b] = wsum[0] + wsum[1] + wsum[2] + wsum[3];
}

__global__ __launch_bounds__(64) void scanB_kernel(const int* __restrict__ partials,
                                                   int* __restrict__ bases)
{
    int l = threadIdx.x;
    int p = (l < 40) ? partials[l] : 0;
    int v = p;
#pragma unroll
    for (int off = 1; off < 64; off <<= 1) {
        int u = __shfl_up(v, off, 64);
        if (l >= off) v += u;
    }
    if (l < 40) bases[l] = v - p;   // exclusive
}

__global__ __launch_bounds__(256) void scanC_kernel(const int* __restrict__ cnt,
                                                    const int* __restrict__ bases,
                                                    int* __restrict__ rps,
                                                    int* __restrict__ rpd,
                                                    float* __restrict__ invd)
{
    int b = blockIdx.x, t = threadIdx.x, lane = t & 63, w = t >> 6;
    int base = b * 1024 + t * 4;
    int v[4], s = 0;
#pragma unroll
    for (int i = 0; i < 4; ++i) {
        int idx = base + i;
        v[i] = (idx < 2 * NN) ? cnt[idx] : 0;
        s += v[i];
    }
    int tsum = s, sc = s;
#pragma unroll
    for (int off = 1; off < 64; off <<= 1) {
        int u = __shfl_up(sc, off, 64);
        if (lane >= off) sc += u;
    }
    __shared__ int wtot[4];
    if (lane == 63) wtot[w] = sc;
    __syncthreads();
    int wbase = 0;
    for (int j = 0; j < w; ++j) wbase += wtot[j];
    int run = bases[b] + wbase + sc - tsum;
#pragma unroll
    for (int i = 0; i < 4; ++i) {
        int idx = base + i;
        int e = run; run += v[i];
        if (idx < NN) {
            rps[idx] = e;
        } else if (idx < 2 * NN) {
            rpd[idx - NN] = e - NE;           // first-half total == NE
            invd[idx - NN] = 1.0f / fmaxf((float)v[i], 1.0f);
        }
    }
    if (b == 0 && t == 0) { rps[NN] = NE; rpd[NN] = NE; }
}

// ---------------- ek MLP + CSR fill ----------------
__global__ __launch_bounds__(256) void ekfill_kernel(
    const int* __restrict__ ei, const float* __restrict__ ea,
    const float* __restrict__ k1w, const float* __restrict__ k1b,
    const int* __restrict__ rps, const int* __restrict__ rpd,
    int* __restrict__ fs, int* __restrict__ fd,
    float* __restrict__ eks, int* __restrict__ ss2sd)
{
    int e = blockIdx.x * 256 + threadIdx.x;
    if (e >= NE) return;
    int s = ei[e], d = ei[NE + e];
    float a[6];
#pragma unroll
    for (int i = 0; i < 6; ++i) a[i] = ea[e * 6 + i];
    int slot_s = rps[s] + atomicAdd(&fs[s], 1);
    int slot_d = rpd[d] + atomicAdd(&fd[d], 1);
    ss2sd[slot_s] = slot_d;
#pragma unroll
    for (int j = 0; j < 16; ++j) {
        float v = k1b[j];
#pragma unroll
        for (int i = 0; i < 6; ++i) v = fmaf(a[i], k1w[i * 16 + j], v);
        eks[(size_t)slot_s * 16 + j] = fmaxf(v, 0.f);
    }
}

// ---------------- GwT hi/lo bf16, [1152 rows n][64 cols k] -----------------
__global__ __launch_bounds__(256) void gwt_kernel(
    const float* __restrict__ k2w, const float* __restrict__ k2b,
    const float* __restrict__ rootw,
    unsigned short* __restrict__ Gh, unsigned short* __restrict__ Gl)
{
    int idx = blockIdx.x * 256 + threadIdx.x;   // 1152*64
    if (idx >= 1152 * 64) return;
    int n = idx >> 6, k = idx & 63;
    int b = n >> 6, o = n & 63;
    float g;
    if (b < 16)       g = k2w[b * 4096 + k * 64 + o];
    else if (b == 16) g = k2b[k * 64 + o];
    else              g = rootw[k * 64 + o];
    unsigned short hi = f2bf(g);
    Gh[idx] = hi;
    Gl[idx] = f2bf(g - bf2f(hi));
}

// ---------------- h0 = x*fc1_w + fc1_b -> hi/lo bf16 ----------------
__global__ __launch_bounds__(256) void h0_kernel(
    const float* __restrict__ x, const float* __restrict__ w,
    const float* __restrict__ b,
    unsigned short* __restrict__ hhi, unsigned short* __restrict__ hlo)
{
    int idx = blockIdx.x * 256 + threadIdx.x;
    if (idx >= NN * WD) return;
    int n = idx >> 6, o = idx & 63;
    float v = fmaf(x[n], w[o], b[o]);
    unsigned short hi = f2bf(v);
    hhi[idx] = hi;
    hlo[idx] = f2bf(v - bf2f(hi));
}

// ---------------- fused: MFMA P->LDS (+Proot->global), then edge combine ----
__global__ __launch_bounds__(512, 4) void fused_kernel(
    const unsigned short* __restrict__ hhi, const unsigned short* __restrict__ hlo,
    const unsigned short* __restrict__ Gh, const unsigned short* __restrict__ Gl,
    const float* __restrict__ eks, const int* __restrict__ ss2sd,
    const int* __restrict__ rps, float* __restrict__ Proot,
    float* __restrict__ msg)
{
    __shared__ __align__(16) float Pt[TM * LSTR];   // 65,520 B
    __shared__ int rb[TM + 1];
    int n0 = blockIdx.x * TM;
    int w = threadIdx.x >> 6, l = threadIdx.x & 63;
    int quad = l >> 4, lr = l & 15;
    if (threadIdx.x < TM + 1) {
        int gi = n0 + threadIdx.x;
        rb[threadIdx.x] = rps[gi > NN ? NN : gi];
    }
    int arow = n0 + lr;
    if (arow > NN - 1) arow = NN - 1;
    const bf16x8* pah = (const bf16x8*)(hhi + (size_t)arow * 64 + quad * 8);
    const bf16x8* pal = (const bf16x8*)(hlo + (size_t)arow * 64 + quad * 8);
    bf16x8 ah0 = pah[0], ah1 = pah[4];   // k 0..31, 32..63
    bf16x8 al0 = pal[0], al1 = pal[4];

    for (int st = w; st < 18; st += 8) {
        f32x4 acc[4];
#pragma unroll
        for (int t = 0; t < 4; ++t) acc[t] = (f32x4){0.f, 0.f, 0.f, 0.f};
#pragma unroll
        for (int t = 0; t < 4; ++t) {
            int brow = st * 64 + t * 16 + lr;
            const bf16x8* pbh = (const bf16x8*)(Gh + (size_t)brow * 64 + quad * 8);
            const bf16x8* pbl = (const bf16x8*)(Gl + (size_t)brow * 64 + quad * 8);
            bf16x8 bh0 = pbh[0], bh1 = pbh[4];
            bf16x8 bl0 = pbl[0], bl1 = pbl[4];
            f32x4 a = acc[t];
            a = __builtin_amdgcn_mfma_f32_16x16x32_bf16(ah0, bh0, a, 0, 0, 0);
            a = __builtin_amdgcn_mfma_f32_16x16x32_bf16(ah0, bl0, a, 0, 0, 0);
            a = __builtin_amdgcn_mfma_f32_16x16x32_bf16(al0, bh0, a, 0, 0, 0);
            a = __builtin_amdgcn_mfma_f32_16x16x32_bf16(ah1, bh1, a, 0, 0, 0);
            a = __builtin_amdgcn_mfma_f32_16x16x32_bf16(ah1, bl1, a, 0, 0, 0);
            a = __builtin_amdgcn_mfma_f32_16x16x32_bf16(al1, bh1, a, 0, 0, 0);
            acc[t] = a;
        }
        // C/D layout: col = lane&15, row = quad*4 + reg
        if (st < 17) {
#pragma unroll
            for (int t = 0; t < 4; ++t)
#pragma unroll
                for (int r = 0; r < 4; ++r) {
                    int row = quad * 4 + r;
                    if (row < TM)
                        Pt[row * LSTR + st * 64 + t * 16 + lr] = acc[t][r];
                }
        } else {
#pragma unroll
            for (int t = 0; t < 4; ++t)
#pragma unroll
                for (int r = 0; r < 4; ++r) {
                    int row = quad * 4 + r;
                    int gn = n0 + row;
                    if (row < TM && gn < NN)
                        Proot[(size_t)gn * 64 + t * 16 + lr] = acc[t][r];
                }
        }
    }
    __syncthreads();

    // edge phase: per-wave contiguous slot sub-range, two-level loop,
    // per-lane (vector-path) eks/ss2sd loads, 2x unrolled for MLP.
    int nend = n0 + TM; if (nend > NN) nend = NN;
    int tmeff = nend - n0;
    int r0 = rb[0], r1 = rb[tmeff];
    int total = r1 - r0;
    if (total <= 0) return;
    int per = (total + 7) >> 3;
    int s0 = r0 + w * per;
    int s1 = s0 + per; if (s1 > r1) s1 = r1;
    for (int ln = 0; ln < tmeff && s0 < s1; ++ln) {
        int lo = s0 > rb[ln] ? s0 : rb[ln];
        int hi = s1 < rb[ln + 1] ? s1 : rb[ln + 1];
        if (lo >= hi) continue;
        float p[17];
        const float* Pr = &Pt[ln * LSTR];
#pragma unroll
        for (int k = 0; k < 17; ++k) p[k] = Pr[k * 64 + l];
        int s = lo;
        for (; s + 1 < hi; s += 2) {
            const float* er = eks + (size_t)s * 16;
            f32x4 a0 = *(const f32x4*)(er);
            f32x4 a1 = *(const f32x4*)(er + 4);
            f32x4 a2 = *(const f32x4*)(er + 8);
            f32x4 a3 = *(const f32x4*)(er + 12);
            f32x4 b0 = *(const f32x4*)(er + 16);
            f32x4 b1 = *(const f32x4*)(er + 20);
            f32x4 b2 = *(const f32x4*)(er + 24);
            f32x4 b3 = *(const f32x4*)(er + 28);
            int d0 = ss2sd[s], d1 = ss2sd[s + 1];
            float ma = p[16], mb = 0.f, na = p[16], nb = 0.f;
            ma = fmaf(a0[0], p[0], ma);  mb = fmaf(a0[1], p[1], mb);
            na = fmaf(b0[0], p[0], na);  nb = fmaf(b0[1], p[1], nb);
            ma = fmaf(a0[2], p[2], ma);  mb = fmaf(a0[3], p[3], mb);
            na = fmaf(b0[2], p[2], na);  nb = fmaf(b0[3], p[3], nb);
            ma = fmaf(a1[0], p[4], ma);  mb = fmaf(a1[1], p[5], mb);
            na = fmaf(b1[0], p[4], na);  nb = fmaf(b1[1], p[5], nb);
            ma = fmaf(a1[2], p[6], ma);  mb = fmaf(a1[3], p[7], mb);
            na = fmaf(b1[2], p[6], na);  nb = fmaf(b1[3], p[7], nb);
            ma = fmaf(a2[0], p[8], ma);  mb = fmaf(a2[1], p[9], mb);
            na = fmaf(b2[0], p[8], na);  nb = fmaf(b2[1], p[9], nb);
            ma = fmaf(a2[2], p[10], ma); mb = fmaf(a2[3], p[11], mb);
            na = fmaf(b2[2], p[10], na); nb = fmaf(b2[3], p[11], nb);
            ma = fmaf(a3[0], p[12], ma); mb = fmaf(a3[1], p[13], mb);
            na = fmaf(b3[0], p[12], na); nb = fmaf(b3[1], p[13], nb);
            ma = fmaf(a3[2], p[14], ma); mb = fmaf(a3[3], p[15], mb);
            na = fmaf(b3[2], p[14], na); nb = fmaf(b3[3], p[15], nb);
            msg[(size_t)d0 * 64 + l] = ma + mb;
            msg[(size_t)d1 * 64 + l] = na + nb;
        }
        if (s < hi) {
            const float* er = eks + (size_t)s * 16;
            f32x4 a0 = *(const f32x4*)(er);
            f32x4 a1 = *(const f32x4*)(er + 4);
            f32x4 a2 = *(const f32x4*)(er + 8);
            f32x4 a3 = *(const f32x4*)(er + 12);
            int d0 = ss2sd[s];
            float ma = p[16], mb = 0.f;
            ma = fmaf(a0[0], p[0], ma);  mb = fmaf(a0[1], p[1], mb);
            ma = fmaf(a0[2], p[2], ma);  mb = fmaf(a0[3], p[3], mb);
            ma = fmaf(a1[0], p[4], ma);  mb = fmaf(a1[1], p[5], mb);
            ma = fmaf(a1[2], p[6], ma);  mb = fmaf(a1[3], p[7], mb);
            ma = fmaf(a2[0], p[8], ma);  mb = fmaf(a2[1], p[9], mb);
            ma = fmaf(a2[2], p[10], ma); mb = fmaf(a2[3], p[11], mb);
            ma = fmaf(a3[0], p[12], ma); mb = fmaf(a3[1], p[13], mb);
            ma = fmaf(a3[2], p[14], ma); mb = fmaf(a3[3], p[15], mb);
            msg[(size_t)d0 * 64 + l] = ma + mb;
        }
    }
}

// ---------------- per-dst sum (coalesced, 4-way ILP) + fused epilogue -------
__global__ __launch_bounds__(256) void agg_kernel(
    const float* __restrict__ msg, const int* __restrict__ rpd,
    const float* __restrict__ invd, const float* __restrict__ Proot,
    const float* __restrict__ convb, float* __restrict__ h,
    unsigned short* __restrict__ hhi, unsigned short* __restrict__ hlo)
{
    int i = blockIdx.x * 4 + (threadIdx.x >> 6);
    if (i >= NN) return;
    int l = threadIdx.x & 63;
    int r0 = rpd[i], r1 = rpd[i + 1];
    float a0 = 0.f, a1 = 0.f, a2 = 0.f, a3 = 0.f;
    int s = r0;
    for (; s + 3 < r1; s += 4) {
        a0 += msg[(size_t)s * 64 + l];
        a1 += msg[(size_t)(s + 1) * 64 + l];
        a2 += msg[(size_t)(s + 2) * 64 + l];
        a3 += msg[(size_t)(s + 3) * 64 + l];
    }
    for (; s < r1; ++s) a0 += msg[(size_t)s * 64 + l];
    float acc = (a0 + a1) + (a2 + a3);
    float v = fmaf(acc, invd[i], Proot[(size_t)i * 64 + l] + convb[l]);
    v = fmaxf(v, 0.f);
    int idx = i * 64 + l;
    h[idx] = v;
    unsigned short hi = f2bf(v);
    hhi[idx] = hi;
    hlo[idx] = f2bf(v - bf2f(hi));
}

// ---------------- out = h @ fc2_w + fc2_b ----------------
__global__ __launch_bounds__(256) void out_kernel(
    const float* __restrict__ h, const float* __restrict__ fc2_w,
    const float* __restrict__ fc2_b, float* __restrict__ out)
{
    int wave = blockIdx.x * 4 + (threadIdx.x >> 6);
    int lane = threadIdx.x & 63;
    float v = h[(size_t)wave * 64 + lane] * fc2_w[lane];
#pragma unroll
    for (int off = 32; off > 0; off >>= 1) v += __shfl_down(v, off);
    if (lane == 0) out[wave] = v + fc2_b[0];
}

extern "C" void kernel_launch(void* const* d_in, const int* in_sizes, int n_in,
                              void* d_out, int out_size, void* d_ws, size_t ws_size,
                              hipStream_t stream)
{
    const float* x         = (const float*)d_in[0];
    const int*   ei        = (const int*)  d_in[1];
    const float* edge_attr = (const float*)d_in[2];
    const float* fc1_w     = (const float*)d_in[3];
    const float* fc1_b     = (const float*)d_in[4];
    const float* k1_w      = (const float*)d_in[5];
    const float* k1_b      = (const float*)d_in[6];
    const float* k2_w      = (const float*)d_in[7];
    const float* k2_b      = (const float*)d_in[8];
    const float* root_w    = (const float*)d_in[9];
    const float* conv_b    = (const float*)d_in[10];
    const float* fc2_w     = (const float*)d_in[11];
    const float* fc2_b     = (const float*)d_in[12];
    float* out = (float*)d_out;

    // workspace layout, f32 units
    float* ws = (float*)d_ws;
    size_t off = 0;
    int* cnt   = (int*)(ws + off); off += 4 * NN;       // outc|inc|fs|fd
    int* outc  = cnt;
    int* inc   = cnt + NN;
    int* fs    = cnt + 2 * NN;
    int* fd    = cnt + 3 * NN;
    int* rps   = (int*)(ws + off); off += 20004;
    int* rpd   = (int*)(ws + off); off += 20004;
    int* partials = (int*)(ws + off); off += 64;
    int* bases    = (int*)(ws + off); off += 64;
    int* ss2sd    = (int*)(ws + off); off += NE;
    float* invd  = ws + off; off += NN;
    float* eks   = ws + off; off += (size_t)NE * 16;
    unsigned short* Gh  = (unsigned short*)(ws + off); off += 36864;
    unsigned short* Gl  = (unsigned short*)(ws + off); off += 36864;
    unsigned short* hhi = (unsigned short*)(ws + off); off += (size_t)NN * 32;
    unsigned short* hlo = (unsigned short*)(ws + off); off += (size_t)NN * 32;
    float* h     = ws + off; off += (size_t)NN * WD;
    float* msg   = ws + off; off += (size_t)NE * WD;
    float* Proot = ws + off; off += (size_t)NN * WD;

    hipMemsetAsync(cnt, 0, 4 * NN * sizeof(int), stream);
    count_kernel<<<(NE + 255) / 256, 256, 0, stream>>>(ei, outc, inc);
    scanA_kernel<<<40, 256, 0, stream>>>(cnt, partials);
    scanB_kernel<<<1, 64, 0, stream>>>(partials, bases);
    scanC_kernel<<<40, 256, 0, stream>>>(cnt, bases, rps, rpd, invd);
    ekfill_kernel<<<(NE + 255) / 256, 256, 0, stream>>>(ei, edge_attr, k1_w, k1_b,
                                                        rps, rpd, fs, fd, eks, ss2sd);
    gwt_kernel<<<(1152 * 64 + 255) / 256, 256, 0, stream>>>(k2_w, k2_b, root_w, Gh, Gl);
    h0_kernel<<<(NN * WD + 255) / 256, 256, 0, stream>>>(x, fc1_w, fc1_b, hhi, hlo);

    int ntiles = (NN + TM - 1) / TM;   // 1334
    for (int layer = 0; layer < DEPTH; ++layer) {
        fused_kernel<<<ntiles, 512, 0, stream>>>(hhi, hlo, Gh, Gl, eks, ss2sd,
                                                 rps, Proot, msg);
        agg_kernel<<<(NN + 3) / 4, 256, 0, stream>>>(msg, rpd, invd, Proot,
                                                     conv_b, h, hhi, hlo);
    }

    out_kernel<<<NN / 4, 256, 0, stream>>>(h, fc2_w, fc2_b, out);
}